// Round 6
// baseline (84.056 us; speedup 1.0000x reference)
//
#include <hip/hip_runtime.h>

#define H  544
#define W  960
#define T  8
#define R  4
#define HB (H / T)    // 68
#define WB (W / T)    // 120
#define NB (HB * WB)  // 8160
#define NC 81         // (2R+1)^2
#define WIN 16        // T + 2R
#define TAG 0x51C0u

__device__ __forceinline__ int iclamp(int v, int lo, int hi) {
    return v < lo ? lo : (v > hi ? hi : v);
}

// ---- compile-time spiral table: rank (0-based) -> cell packed (wy<<4)|wx ----
struct SpiralTab { int v[NC]; };

__host__ __device__ constexpr SpiralTab make_spiral() {
    SpiralTab t{};
    int n = 0;
    for (int dy = 0; dy <= R; ++dy) {
        for (int dir = 0; dir < 4; ++dir) {
            int limit = (dir == 0 && dy == 0) ? 1 : dy;
            for (int dx = -dy; dx < limit; ++dx) {
                int wx, wy;
                if (dir == 0)      { wx = R + dx; wy = R + dy; }
                else if (dir == 1) { wx = R + dy; wy = R - dx; }
                else if (dir == 2) { wx = R - dx; wy = R - dy; }
                else               { wx = R - dy; wy = R + dx; }
                t.v[n] = (wy << 4) | wx;
                ++n;
            }
        }
    }
    return t;
}

static __constant__ SpiralTab SPIR = make_spiral();

__device__ __forceinline__ unsigned int sadu8(unsigned int a, unsigned int b, unsigned int acc) {
#if __has_builtin(__builtin_amdgcn_sad_u8)
    return __builtin_amdgcn_sad_u8(a, b, acc);
#else
    unsigned int d;
    asm("v_sad_u8 %0, %1, %2, %3" : "=v"(d) : "v"(a), "v"(b), "v"(acc));
    return d;
#endif
}

__device__ __forceinline__ unsigned int alignb(unsigned int hi, unsigned int lo, unsigned int sh) {
#if __has_builtin(__builtin_amdgcn_alignbyte)
    return __builtin_amdgcn_alignbyte(hi, lo, sh);
#else
    unsigned int d;
    asm("v_alignbyte_b32 %0, %1, %2, %3" : "=v"(d) : "v"(hi), "v"(lo), "v"(sh));
    return d;
#endif
}

// ============ K1: binomial blur + uint8 quantize, 4 px / thread ============
// Exact fp32 association ((top + 2*mid) + bot)*0.25, no FMA contraction.
__global__ void __launch_bounds__(256)
k_blur(const float* __restrict__ cur, const float* __restrict__ prev,
       float* __restrict__ cur_blur,
       unsigned char* __restrict__ cur_q,
       unsigned char* __restrict__ prev_q) {
    int img = blockIdx.y;
    int p   = blockIdx.x * 256 + threadIdx.x;   // 0 .. H*240-1
    int y  = p / 240;
    int xq = p % 240;
    int x0 = xq * 4;
    const float* src = (img == 0) ? cur : prev;
    int ym = iclamp(y - 1, 0, H - 1) * W;
    int y0 = y * W;
    int yp = iclamp(y + 1, 0, H - 1) * W;
    int xl = (x0 == 0) ? 0 : x0 - 1;
    int xr = (x0 + 4 > W - 1) ? W - 1 : x0 + 4;

    float4 rm = *(const float4*)(src + ym + x0);
    float4 rc = *(const float4*)(src + y0 + x0);
    float4 rp = *(const float4*)(src + yp + x0);
    float lm = src[ym + xl], lc = src[y0 + xl], lp = src[yp + xl];
    float em = src[ym + xr], ec = src[y0 + xr], ep = src[yp + xr];

#define VERT(a, b, c) (__fmul_rn(__fadd_rn(__fadd_rn((a), __fmul_rn(2.0f, (b))), (c)), 0.25f))
    float vL = VERT(lm, lc, lp);
    float v0 = VERT(rm.x, rc.x, rp.x);
    float v1 = VERT(rm.y, rc.y, rp.y);
    float v2 = VERT(rm.z, rc.z, rp.z);
    float v3 = VERT(rm.w, rc.w, rp.w);
    float vR = VERT(em, ec, ep);
    float h0 = VERT(vL, v0, v1);
    float h1 = VERT(v0, v1, v2);
    float h2 = VERT(v1, v2, v3);
    float h3 = VERT(v2, v3, vR);
#undef VERT
#define QU(h) ((unsigned int)fminf(fmaxf(rintf(__fmul_rn((h), 255.0f)), 0.0f), 255.0f))
    unsigned int packed = QU(h0) | (QU(h1) << 8) | (QU(h2) << 16) | (QU(h3) << 24);
#undef QU
    if (img == 0) {
        *(float4*)(cur_blur + y0 + x0) = make_float4(h0, h1, h2, h3);
        *(unsigned int*)(cur_q + y0 + x0) = packed;
    } else {
        *(unsigned int*)(prev_q + y0 + x0) = packed;
    }
}

__device__ __forceinline__ void msort(float& a, float& b) {
    float mn = fminf(a, b), mx = fmaxf(a, b);
    a = mn; b = mx;
}

__device__ __forceinline__ float median9(float p[9]) {
    msort(p[1], p[2]); msort(p[4], p[5]); msort(p[7], p[8]);
    msort(p[0], p[1]); msort(p[3], p[4]); msort(p[6], p[7]);
    msort(p[1], p[2]); msort(p[4], p[5]); msort(p[7], p[8]);
    msort(p[0], p[3]); msort(p[5], p[8]); msort(p[4], p[7]);
    msort(p[3], p[6]); msort(p[1], p[4]); msort(p[2], p[5]);
    msort(p[4], p[7]); msort(p[4], p[2]); msort(p[6], p[4]);
    msort(p[4], p[2]);
    return p[4];
}

__device__ __forceinline__ unsigned int wait_word(unsigned int* p) {
    unsigned int v = __hip_atomic_load(p, __ATOMIC_RELAXED, __HIP_MEMORY_SCOPE_AGENT);
    while ((v >> 16) != TAG) {
        __builtin_amdgcn_s_sleep(1);
        v = __hip_atomic_load(p, __ATOMIC_RELAXED, __HIP_MEMORY_SCOPE_AGENT);
    }
    return v;
}

// ============ K2: fused SAD + spiral argmin + median + Lucas-Kanade ============
// One wave per 8x8 block, 2040 wgs x 4 waves. Phase 1 (SAD) stores a tagged
// u32 per block (data rides in the word, AGENT-scope relaxed). Phase 2 spins
// on the 9 neighbor words, then median + LK using the LDS-staged bytes.
// __launch_bounds__(256,8): capacity 8 wg/CU * 256 CUs = 2048 >= 2040 resident,
// and all stores precede all spins, so the spin cannot deadlock.
__global__ void __launch_bounds__(256, 8)
k_sadflow(const unsigned char* __restrict__ cur_q,
          const unsigned char* __restrict__ prev_q,
          const float* __restrict__ cur_blur,
          unsigned int* __restrict__ vecw,
          float* __restrict__ out) {
    __shared__ uint4 region[4][WIN];   // 16 rows x 16 B, packed prev bytes
    __shared__ uint2 tmplS[4][T];      // 8 rows x 8 B, packed cur bytes
    const int wv   = (int)(threadIdx.x >> 6);
    const int lane = (int)(threadIdx.x & 63);
    const int bidx = (int)blockIdx.x * 4 + wv;    // NB = 2040*4, exact
    const int byi = bidx / WB, bxi = bidx % WB;
    const int by0 = byi * T, bx0 = bxi * T;

    // stage region: lane -> word (ry = lane>>2, wx = lane&3)
    {
        int ry = lane >> 2, wx = lane & 3;
        int gy = iclamp(by0 - R + ry, 0, H - 1);
        unsigned int word;
        if (bxi > 0 && bxi < WB - 1) {
            word = *(const unsigned int*)(prev_q + gy * W + (bx0 - 4 + wx * 4));
        } else {
            int xb = bx0 - 4 + wx * 4;
            unsigned int b0 = prev_q[gy * W + iclamp(xb + 0, 0, W - 1)];
            unsigned int b1 = prev_q[gy * W + iclamp(xb + 1, 0, W - 1)];
            unsigned int b2 = prev_q[gy * W + iclamp(xb + 2, 0, W - 1)];
            unsigned int b3 = prev_q[gy * W + iclamp(xb + 3, 0, W - 1)];
            word = b0 | (b1 << 8) | (b2 << 16) | (b3 << 24);
        }
        ((unsigned int*)&region[wv][0])[lane] = word;
    }
    if (lane < 16) {
        int ty = lane >> 1, half = lane & 1;
        ((unsigned int*)&tmplS[wv][0])[lane] =
            *(const unsigned int*)(cur_q + (by0 + ty) * W + bx0 + half * 4);
    }
    __syncthreads();

    // ---- phase 1: SAD, lane = spiral rank (ranks {lane, lane+64}) ----
    int cell0 = SPIR.v[lane];
    int dy0 = cell0 >> 4, dx0 = cell0 & 15;
    bool v1 = (lane + 64) < NC;
    int cell1 = SPIR.v[v1 ? (lane + 64) : 0];
    int dy1 = cell1 >> 4, dx1 = cell1 & 15;

    unsigned int sad0 = 0, sad1 = 0;
    int q0 = dx0 >> 2; unsigned int r0 = (unsigned int)(dx0 & 3);
    int q1 = dx1 >> 2; unsigned int r1 = (unsigned int)(dx1 & 3);
#pragma unroll
    for (int ty = 0; ty < T; ++ty) {
        uint2 tt = tmplS[wv][ty];
        {
            uint4 row = region[wv][ty + dy0];
            unsigned int w0 = (q0 == 0) ? row.x : ((q0 == 1) ? row.y : row.z);
            unsigned int w1 = (q0 == 0) ? row.y : ((q0 == 1) ? row.z : row.w);
            unsigned int w2 = (q0 == 0) ? row.z : row.w;
            sad0 = sadu8(alignb(w1, w0, r0), tt.x, sad0);
            sad0 = sadu8(alignb(w2, w1, r0), tt.y, sad0);
        }
        if (v1) {
            uint4 row = region[wv][ty + dy1];
            unsigned int w0 = (q1 == 0) ? row.x : ((q1 == 1) ? row.y : row.z);
            unsigned int w1 = (q1 == 0) ? row.y : ((q1 == 1) ? row.z : row.w);
            unsigned int w2 = (q1 == 0) ? row.z : row.w;
            sad1 = sadu8(alignb(w1, w0, r1), tt.x, sad1);
            sad1 = sadu8(alignb(w2, w1, r1), tt.y, sad1);
        }
    }
    int key = (int)((sad0 << 7) | (unsigned int)lane);
    if (v1) {
        int k1 = (int)((sad1 << 7) | (unsigned int)(lane + 64));
        key = min(key, k1);
    }
#pragma unroll
    for (int off = 32; off > 0; off >>= 1)
        key = min(key, __shfl_xor(key, off));
    if (lane == 0) {
        int rank = key & 127;
        int cell = SPIR.v[rank];
        int vy = -((cell >> 4) - R);    // in [-4,4]
        int vx = -((cell & 15) - R);
        unsigned int word = (TAG << 16) | ((unsigned int)(vy + 8) << 8) | (unsigned int)(vx + 8);
        __hip_atomic_store(&vecw[bidx], word, __ATOMIC_RELAXED, __HIP_MEMORY_SCOPE_AGENT);
    }

    // ---- phase 2: median (spin on 9 neighbor words) + Lucas-Kanade ----
    float py[9], px[9];
#pragma unroll
    for (int i = 0; i < 3; ++i)
#pragma unroll
        for (int j = 0; j < 3; ++j) {
            int nb = iclamp(byi + i - 1, 0, HB - 1) * WB + iclamp(bxi + j - 1, 0, WB - 1);
            unsigned int wd = wait_word(&vecw[nb]);
            py[i * 3 + j] = (float)((int)((wd >> 8) & 255u) - 8);
            px[i * 3 + j] = (float)((int)(wd & 255u) - 8);
        }
    float vmy = median9(py);
    float vmx = median9(px);

    int med_y = iclamp((int)rintf(vmy), -R, R);
    int med_x = iclamp((int)rintf(vmx), -R, R);
    int off_y = -med_y, off_x = -med_x;   // vec stores negated offsets

    // border-ring pixel for this lane (28 active lanes)
    bool act = lane < 28;
    int k = act ? lane : 0;
    int rty, rtx;
    if (k < 8)       { rty = 0;      rtx = k;      }
    else if (k < 16) { rty = T - 1;  rtx = k - 8;  }
    else if (k < 22) { rty = k - 15; rtx = 0;      }
    else             { rty = k - 21; rtx = T - 1;  }

    float a = 0.f, b = 0.f, d = 0.f, p = 0.f, q = 0.f;
    if (act) {
        int y = by0 + rty, x = bx0 + rtx;
        // template byte from LDS (== cur_q[y*W+x])
        unsigned int tb = ((const unsigned char*)&tmplS[wv][0])[rty * 8 + rtx];
        float tmplv = (float)tb / 255.0f;
        // matched byte from LDS region row (== prev_q[clamp(y+off_y)][clamp(x+off_x)];
        // region row ry holds prev_q[clamp(by0-4+ry)] with per-byte column clamp)
        int ridx = rty + off_y + 4;          // in [0,15]
        int cidx = rtx + off_x + 4;          // in [0,15]
        uint4 row = region[wv][ridx];
        unsigned int wsel = (cidx >> 2) == 0 ? row.x
                          : ((cidx >> 2) == 1 ? row.y
                          : ((cidx >> 2) == 2 ? row.z : row.w));
        unsigned int mb = (wsel >> ((cidx & 3) * 8)) & 255u;
        float matv = (float)mb / 255.0f;
        float gyv = (cur_blur[iclamp(y + 1, 0, H - 1) * W + x]
                   - cur_blur[iclamp(y - 1, 0, H - 1) * W + x]) * 0.5f;
        float gxv = (cur_blur[y * W + iclamp(x + 1, 0, W - 1)]
                   - cur_blur[y * W + iclamp(x - 1, 0, W - 1)]) * 0.5f;
        float diff = matv - tmplv;
        a = gxv * gxv;
        b = gxv * gyv;
        d = gyv * gyv;
        p = diff * gxv;
        q = diff * gyv;
    }
#pragma unroll
    for (int off = 16; off > 0; off >>= 1) {
        a += __shfl_xor(a, off);
        b += __shfl_xor(b, off);
        d += __shfl_xor(d, off);
        p += __shfl_xor(p, off);
        q += __shfl_xor(q, off);
    }
    if (lane == 0) {
        float det  = a * d - b * b;
        float safe = (det <= 1e-6f) ? 1.0f : det;
        float su = (d * p - b * q) / safe;
        float sv = (a * q - b * p) / safe;
        bool inval = (det <= 1e-6f);
        float sy = (inval || fabsf(sv) >= 1.0f) ? 0.0f : sv;
        float sx = (inval || fabsf(su) >= 1.0f) ? 0.0f : su;
        out[bidx]      = vmy + sy;
        out[NB + bidx] = vmx + sx;
    }
}

extern "C" void kernel_launch(void* const* d_in, const int* in_sizes, int n_in,
                              void* d_out, int out_size, void* d_ws, size_t ws_size,
                              hipStream_t stream) {
    const float* cur  = (const float*)d_in[0];
    const float* prev = (const float*)d_in[1];
    float* out = (float*)d_out;

    char* ws = (char*)d_ws;
    float*         cur_blur = (float*)ws;                               // H*W f32
    unsigned char* cur_q    = (unsigned char*)(ws + (size_t)H * W * 4); // H*W u8
    unsigned char* prev_q   = cur_q + (size_t)H * W;                    // H*W u8
    unsigned int*  vecw     = (unsigned int*)(ws + (size_t)H * W * 6);  // NB tagged words

    k_blur<<<dim3(H * 240 / 256, 2), 256, 0, stream>>>(cur, prev, cur_blur, cur_q, prev_q);
    k_sadflow<<<NB / 4, 256, 0, stream>>>(cur_q, prev_q, cur_blur, vecw, out);
}

// Round 7
// 74.901 us; speedup vs baseline: 1.1222x; 1.1222x over previous
//
#include <hip/hip_runtime.h>

#define H  544
#define W  960
#define T  8
#define R  4
#define HB (H / T)    // 68
#define WB (W / T)    // 120
#define NB (HB * WB)  // 8160
#define NC 81         // (2R+1)^2
#define WIN 16        // T + 2R

__device__ __forceinline__ int iclamp(int v, int lo, int hi) {
    return v < lo ? lo : (v > hi ? hi : v);
}

// ---- compile-time spiral table: rank (0-based) -> cell packed (wy<<4)|wx ----
struct SpiralTab { int v[NC]; };

__host__ __device__ constexpr SpiralTab make_spiral() {
    SpiralTab t{};
    int n = 0;
    for (int dy = 0; dy <= R; ++dy) {
        for (int dir = 0; dir < 4; ++dir) {
            int limit = (dir == 0 && dy == 0) ? 1 : dy;
            for (int dx = -dy; dx < limit; ++dx) {
                int wx, wy;
                if (dir == 0)      { wx = R + dx; wy = R + dy; }
                else if (dir == 1) { wx = R + dy; wy = R - dx; }
                else if (dir == 2) { wx = R - dx; wy = R - dy; }
                else               { wx = R - dy; wy = R + dx; }
                t.v[n] = (wy << 4) | wx;
                ++n;
            }
        }
    }
    return t;
}

static __constant__ SpiralTab SPIR = make_spiral();

__device__ __forceinline__ unsigned int sadu8(unsigned int a, unsigned int b, unsigned int acc) {
#if __has_builtin(__builtin_amdgcn_sad_u8)
    return __builtin_amdgcn_sad_u8(a, b, acc);
#else
    unsigned int d;
    asm("v_sad_u8 %0, %1, %2, %3" : "=v"(d) : "v"(a), "v"(b), "v"(acc));
    return d;
#endif
}

__device__ __forceinline__ unsigned int alignb(unsigned int hi, unsigned int lo, unsigned int sh) {
#if __has_builtin(__builtin_amdgcn_alignbyte)
    return __builtin_amdgcn_alignbyte(hi, lo, sh);
#else
    unsigned int d;
    asm("v_alignbyte_b32 %0, %1, %2, %3" : "=v"(d) : "v"(hi), "v"(lo), "v"(sh));
    return d;
#endif
}

// ============ K1: binomial blur + uint8 quantize, 4 px / thread ============
// Exact fp32 association ((top + 2*mid) + bot)*0.25, no FMA contraction.
__global__ void __launch_bounds__(256)
k_blur(const float* __restrict__ cur, const float* __restrict__ prev,
       float* __restrict__ cur_blur,
       unsigned char* __restrict__ cur_q,
       unsigned char* __restrict__ prev_q) {
    int img = blockIdx.y;
    int p   = blockIdx.x * 256 + threadIdx.x;   // 0 .. H*240-1
    int y  = p / 240;
    int xq = p % 240;
    int x0 = xq * 4;
    const float* src = (img == 0) ? cur : prev;
    int ym = iclamp(y - 1, 0, H - 1) * W;
    int y0 = y * W;
    int yp = iclamp(y + 1, 0, H - 1) * W;
    int xl = (x0 == 0) ? 0 : x0 - 1;
    int xr = (x0 + 4 > W - 1) ? W - 1 : x0 + 4;

    float4 rm = *(const float4*)(src + ym + x0);
    float4 rc = *(const float4*)(src + y0 + x0);
    float4 rp = *(const float4*)(src + yp + x0);
    float lm = src[ym + xl], lc = src[y0 + xl], lp = src[yp + xl];
    float em = src[ym + xr], ec = src[y0 + xr], ep = src[yp + xr];

#define VERT(a, b, c) (__fmul_rn(__fadd_rn(__fadd_rn((a), __fmul_rn(2.0f, (b))), (c)), 0.25f))
    float vL = VERT(lm, lc, lp);
    float v0 = VERT(rm.x, rc.x, rp.x);
    float v1 = VERT(rm.y, rc.y, rp.y);
    float v2 = VERT(rm.z, rc.z, rp.z);
    float v3 = VERT(rm.w, rc.w, rp.w);
    float vR = VERT(em, ec, ep);
    float h0 = VERT(vL, v0, v1);
    float h1 = VERT(v0, v1, v2);
    float h2 = VERT(v1, v2, v3);
    float h3 = VERT(v2, v3, vR);
#undef VERT
#define QU(h) ((unsigned int)fminf(fmaxf(rintf(__fmul_rn((h), 255.0f)), 0.0f), 255.0f))
    unsigned int packed = QU(h0) | (QU(h1) << 8) | (QU(h2) << 16) | (QU(h3) << 24);
#undef QU
    if (img == 0) {
        *(float4*)(cur_blur + y0 + x0) = make_float4(h0, h1, h2, h3);
        *(unsigned int*)(cur_q + y0 + x0) = packed;
    } else {
        *(unsigned int*)(prev_q + y0 + x0) = packed;
    }
}

// ============ K2: 81-candidate SAD + spiral tie-break, packed bytes ============
// One wave per 8x8 block; lane = spiral rank (lane handles ranks {lane, lane+64}).
__global__ void __launch_bounds__(256)
k_sad(const unsigned char* __restrict__ cur_q,
      const unsigned char* __restrict__ prev_q,
      float* __restrict__ vecy, float* __restrict__ vecx) {
    __shared__ uint4 region[4][WIN];   // 16 rows x 16 B, packed
    __shared__ uint2 tmplS[4][T];      // 8 rows x 8 B
    int w    = threadIdx.x >> 6;
    int lane = threadIdx.x & 63;
    int bidx = blockIdx.x * 4 + w;     // NB = 2040*4, exact
    int byi = bidx / WB, bxi = bidx % WB;
    int by0 = byi * T, bx0 = bxi * T;

    // stage region: lane -> word (ry = lane>>2, wx = lane&3)
    {
        int ry = lane >> 2, wx = lane & 3;
        int gy = iclamp(by0 - R + ry, 0, H - 1);
        unsigned int word;
        if (bxi > 0 && bxi < WB - 1) {
            word = *(const unsigned int*)(prev_q + gy * W + (bx0 - 4 + wx * 4));
        } else {
            int xb = bx0 - 4 + wx * 4;
            unsigned int b0 = prev_q[gy * W + iclamp(xb + 0, 0, W - 1)];
            unsigned int b1 = prev_q[gy * W + iclamp(xb + 1, 0, W - 1)];
            unsigned int b2 = prev_q[gy * W + iclamp(xb + 2, 0, W - 1)];
            unsigned int b3 = prev_q[gy * W + iclamp(xb + 3, 0, W - 1)];
            word = b0 | (b1 << 8) | (b2 << 16) | (b3 << 24);
        }
        ((unsigned int*)&region[w][0])[lane] = word;
    }
    // stage template (8B-aligned rows)
    if (lane < 16) {
        int ty = lane >> 1, half = lane & 1;
        ((unsigned int*)&tmplS[w][0])[lane] =
            *(const unsigned int*)(cur_q + (by0 + ty) * W + bx0 + half * 4);
    }
    __syncthreads();

    unsigned int t0[T], t1[T];
#pragma unroll
    for (int ty = 0; ty < T; ++ty) {
        uint2 tt = tmplS[w][ty];
        t0[ty] = tt.x;
        t1[ty] = tt.y;
    }

    // candidate SAD for spiral ranks lane and lane+64
    int cell0 = SPIR.v[lane];
    int dy0 = cell0 >> 4, dx0 = cell0 & 15;
    bool v1 = (lane + 64) < NC;
    int cell1 = SPIR.v[v1 ? (lane + 64) : 0];
    int dy1 = cell1 >> 4, dx1 = cell1 & 15;

    unsigned int sad0 = 0, sad1 = 0;
    int q0 = dx0 >> 2; unsigned int r0 = (unsigned int)(dx0 & 3);
    int q1 = dx1 >> 2; unsigned int r1 = (unsigned int)(dx1 & 3);
#pragma unroll
    for (int ty = 0; ty < T; ++ty) {
        {
            uint4 row = region[w][ty + dy0];
            unsigned int w0 = (q0 == 0) ? row.x : ((q0 == 1) ? row.y : row.z);
            unsigned int w1 = (q0 == 0) ? row.y : ((q0 == 1) ? row.z : row.w);
            unsigned int w2 = (q0 == 0) ? row.z : row.w;
            sad0 = sadu8(alignb(w1, w0, r0), t0[ty], sad0);
            sad0 = sadu8(alignb(w2, w1, r0), t1[ty], sad0);
        }
        if (v1) {
            uint4 row = region[w][ty + dy1];
            unsigned int w0 = (q1 == 0) ? row.x : ((q1 == 1) ? row.y : row.z);
            unsigned int w1 = (q1 == 0) ? row.y : ((q1 == 1) ? row.z : row.w);
            unsigned int w2 = (q1 == 0) ? row.z : row.w;
            sad1 = sadu8(alignb(w1, w0, r1), t0[ty], sad1);
            sad1 = sadu8(alignb(w2, w1, r1), t1[ty], sad1);
        }
    }

    // key = (sad<<7) | rank  — lanes are spiral-rank-ordered, so min key
    // is (min sad, earliest spiral).
    int key = (int)((sad0 << 7) | (unsigned int)lane);
    if (v1) {
        int k1 = (int)((sad1 << 7) | (unsigned int)(lane + 64));
        key = min(key, k1);
    }
#pragma unroll
    for (int off = 32; off > 0; off >>= 1)
        key = min(key, __shfl_xor(key, off));
    if (lane == 0) {
        int rank = key & 127;
        int cell = SPIR.v[rank];
        int dyi = (cell >> 4) - R;
        int dxi = (cell & 15) - R;
        vecy[bidx] = (float)(-dyi);
        vecx[bidx] = (float)(-dxi);
    }
}

// ============ K3: median + LK, 32 lanes per block ============
__device__ __forceinline__ void msort(float& a, float& b) {
    float mn = fminf(a, b), mx = fmaxf(a, b);
    a = mn; b = mx;
}

__device__ __forceinline__ float median9(float p[9]) {
    msort(p[1], p[2]); msort(p[4], p[5]); msort(p[7], p[8]);
    msort(p[0], p[1]); msort(p[3], p[4]); msort(p[6], p[7]);
    msort(p[1], p[2]); msort(p[4], p[5]); msort(p[7], p[8]);
    msort(p[0], p[3]); msort(p[5], p[8]); msort(p[4], p[7]);
    msort(p[3], p[6]); msort(p[1], p[4]); msort(p[2], p[5]);
    msort(p[4], p[7]); msort(p[4], p[2]); msort(p[6], p[4]);
    msort(p[4], p[2]);
    return p[4];
}

__global__ void __launch_bounds__(256)
k_flow(const unsigned char* __restrict__ cur_q,
       const unsigned char* __restrict__ prev_q,
       const float* __restrict__ cur_blur,
       const float* __restrict__ vecy, const float* __restrict__ vecx,
       float* __restrict__ out) {
    int bidx = blockIdx.x * 8 + (threadIdx.x >> 5);   // NB = 1020*8, exact
    int lane = threadIdx.x & 31;
    int byi = bidx / WB, bxi = bidx % WB;

    // 3x3 neighbor vectors: lanes 0-8 load one pair each, then broadcast
    // via shfl (width 32 stays within this block's lane group).
    float vy_l = 0.0f, vx_l = 0.0f;
    if (lane < 9) {
        int yy = iclamp(byi + lane / 3 - 1, 0, HB - 1);
        int xx = iclamp(bxi + lane % 3 - 1, 0, WB - 1);
        vy_l = vecy[yy * WB + xx];
        vx_l = vecx[yy * WB + xx];
    }
    float py[9], px[9];
#pragma unroll
    for (int m = 0; m < 9; ++m) {
        py[m] = __shfl(vy_l, m, 32);
        px[m] = __shfl(vx_l, m, 32);
    }
    float vmy = median9(py);
    float vmx = median9(px);

    int med_y = iclamp((int)rintf(vmy), -R, R);
    int med_x = iclamp((int)rintf(vmx), -R, R);
    int off_y = -med_y, off_x = -med_x;   // vec stores negated offsets

    // border-ring pixel for this lane (28 active lanes)
    bool act = lane < 28;
    int k = act ? lane : 0;
    int ty, tx;
    if (k < 8)       { ty = 0;      tx = k;      }
    else if (k < 16) { ty = T - 1;  tx = k - 8;  }
    else if (k < 22) { ty = k - 15; tx = 0;      }
    else             { ty = k - 21; tx = T - 1;  }

    int by0 = byi * T, bx0 = bxi * T;
    int y = by0 + ty, x = bx0 + tx;
    float tmplv = (float)cur_q[y * W + x] / 255.0f;
    int my = iclamp(y + off_y, 0, H - 1);
    int mx = iclamp(x + off_x, 0, W - 1);
    float matv = (float)prev_q[my * W + mx] / 255.0f;
    float gyv = (cur_blur[iclamp(y + 1, 0, H - 1) * W + x]
               - cur_blur[iclamp(y - 1, 0, H - 1) * W + x]) * 0.5f;
    float gxv = (cur_blur[y * W + iclamp(x + 1, 0, W - 1)]
               - cur_blur[y * W + iclamp(x - 1, 0, W - 1)]) * 0.5f;
    float diff = matv - tmplv;

    float a = act ? gxv * gxv : 0.0f;
    float b = act ? gxv * gyv : 0.0f;
    float d = act ? gyv * gyv : 0.0f;
    float p = act ? diff * gxv : 0.0f;
    float q = act ? diff * gyv : 0.0f;
#pragma unroll
    for (int off = 16; off > 0; off >>= 1) {
        a += __shfl_xor(a, off);
        b += __shfl_xor(b, off);
        d += __shfl_xor(d, off);
        p += __shfl_xor(p, off);
        q += __shfl_xor(q, off);
    }

    if (lane == 0) {
        float det  = a * d - b * b;
        float safe = (det <= 1e-6f) ? 1.0f : det;
        float su = (d * p - b * q) / safe;
        float sv = (a * q - b * p) / safe;
        bool inval = (det <= 1e-6f);
        float sy = (inval || fabsf(sv) >= 1.0f) ? 0.0f : sv;
        float sx = (inval || fabsf(su) >= 1.0f) ? 0.0f : su;
        out[bidx]      = vmy + sy;
        out[NB + bidx] = vmx + sx;
    }
}

extern "C" void kernel_launch(void* const* d_in, const int* in_sizes, int n_in,
                              void* d_out, int out_size, void* d_ws, size_t ws_size,
                              hipStream_t stream) {
    const float* cur  = (const float*)d_in[0];
    const float* prev = (const float*)d_in[1];
    float* out = (float*)d_out;

    char* ws = (char*)d_ws;
    float*         cur_blur = (float*)ws;                               // H*W f32
    unsigned char* cur_q    = (unsigned char*)(ws + (size_t)H * W * 4); // H*W u8
    unsigned char* prev_q   = cur_q + (size_t)H * W;                    // H*W u8
    float*         vecy     = (float*)(ws + (size_t)H * W * 6);         // NB f32
    float*         vecx     = vecy + NB;                                // NB f32

    k_blur<<<dim3(H * 240 / 256, 2), 256, 0, stream>>>(cur, prev, cur_blur, cur_q, prev_q);
    k_sad<<<NB / 4, 256, 0, stream>>>(cur_q, prev_q, vecy, vecx);
    k_flow<<<NB / 8, 256, 0, stream>>>(cur_q, prev_q, cur_blur, vecy, vecx, out);
}